// Round 1
// 509.538 us; speedup vs baseline: 1.0682x; 1.0682x over previous
//
#include <hip/hip_runtime.h>
#include <hip/hip_bf16.h>

#define LN_EPS 1e-5f

typedef __attribute__((ext_vector_type(8))) short bf16x8;
typedef __attribute__((ext_vector_type(4))) float f32x4;

static __device__ __forceinline__ unsigned short f2bf(float x) {
    unsigned int u = __float_as_uint(x);
    return (unsigned short)((u + 0x7FFFu + ((u >> 16) & 1u)) >> 16);
}
static __device__ __forceinline__ float bf2f(unsigned short u) {
    return __uint_as_float(((unsigned int)u) << 16);
}
static __device__ __forceinline__ uint2 pack4bf(float a, float b, float c, float d) {
    uint2 r;
    r.x = (unsigned int)f2bf(a) | ((unsigned int)f2bf(b) << 16);
    r.y = (unsigned int)f2bf(c) | ((unsigned int)f2bf(d) << 16);
    return r;
}

// ---------------------------------------------------------------------------
// Weight packers: fragment-ready layout for mfma A-operand.
// Tile (kb, nt), lane l: m = nt*16 + (l&15), k = kb*32 + (l>>4)*8 + i.
// ---------------------------------------------------------------------------
static __device__ __forceinline__ void pack_w_body(
    const float* Wk, const float* Wv, unsigned short* Bp, int Kreal, int idx)
{
    int kb = idx >> 10, rem = idx & 1023, nt = rem >> 6, l = rem & 63;
    int n_g = nt * 16 + (l & 15);
    int kbase = kb * 32 + ((l >> 4) * 8);
    const float* W = (n_g < 128) ? Wk : Wv;
    int n = (n_g < 128) ? n_g : n_g - 128;
    unsigned short o[8];
    #pragma unroll
    for (int i = 0; i < 8; ++i) {
        int k = kbase + i;
        o[i] = (k < Kreal) ? f2bf(W[(size_t)k * 128 + n]) : (unsigned short)0;
    }
    *(int4*)(Bp + (size_t)idx * 8) = *(const int4*)o;
}
static __device__ __forceinline__ void pack_w128_body(
    const float* W, unsigned short* Bp, int Kreal, int idx)
{
    int kb = idx >> 9, rem = idx & 511, nt = rem >> 6, l = rem & 63;
    int n = nt * 16 + (l & 15);
    int kbase = kb * 32 + ((l >> 4) * 8);
    unsigned short o[8];
    #pragma unroll
    for (int i = 0; i < 8; ++i) {
        int k = kbase + i;
        o[i] = (k < Kreal) ? f2bf(W[(size_t)k * 128 + n]) : (unsigned short)0;
    }
    *(int4*)(Bp + (size_t)idx * 8) = *(const int4*)o;
}
// 128-col pack with source-row offset (for the Hd/Hs slices of the fused W1)
static __device__ __forceinline__ void pack_w128_off(
    const float* W, unsigned short* Bp, int idx, int rowoff)
{
    int kb = idx >> 9, rem = idx & 511, nt = rem >> 6, l = rem & 63;
    int n = nt * 16 + (l & 15);
    int kbase = kb * 32 + ((l >> 4) * 8);
    unsigned short o[8];
    #pragma unroll
    for (int i = 0; i < 8; ++i)
        o[i] = f2bf(W[(size_t)(rowoff + kbase + i) * 128 + n]);
    *(int4*)(Bp + (size_t)idx * 8) = *(const int4*)o;
}

// Block map: [0,4) B1e edge-part fused 24K | [4,20) B2p fused 128K |
// [20,52) W1h 4x(128K->128) | [52,60) W1q | [60,68) W2q | [68,84) W1o | [84,92) W2o
__global__ void pack_all_kernel(
    const float* kW1, const float* vW1, const float* kW2, const float* vW2,
    const float* qW1, const float* qW2, const float* oW1, const float* oW2,
    unsigned short* B1e, unsigned short* B2p, unsigned short* W1h,
    unsigned short* W1q, unsigned short* W2q,
    unsigned short* W1o, unsigned short* W2o)
{
    int b = blockIdx.x, tid = threadIdx.x;
    if      (b < 4)  pack_w_body(kW1, vW1, B1e, 24, b * 256 + tid);
    else if (b < 20) pack_w_body(kW2, vW2, B2p, 128, (b - 4) * 256 + tid);
    else if (b < 52) {
        int bb = b - 20, gy = bb >> 3;
        const float* W = (gy == 1 || gy == 3) ? vW1 : kW1;
        int ro = (gy < 2) ? 24 : 152;  // 24..151 = h[dst] rows, 152..279 = h[src]
        pack_w128_off(W, W1h + (size_t)gy * 16384, (bb & 7) * 256 + tid, ro);
    }
    else if (b < 60) pack_w128_body(qW1, W1q, 128, (b - 52) * 256 + tid);
    else if (b < 68) pack_w128_body(qW2, W2q, 128, (b - 60) * 256 + tid);
    else if (b < 84) pack_w128_body(oW1, W1o, 256, (b - 68) * 256 + tid);
    else             pack_w128_body(oW2, W2o, 128, (b - 84) * 256 + tid);
}

// ---------------------------------------------------------------------------
// Node-side MFMA MLP (unchanged): out = ReLU(LN(x@W1+b1))@W2+b2, 128 rows/blk.
// ---------------------------------------------------------------------------
template<int DIN, typename OUT>
__global__ __launch_bounds__(256, 2) void node_mlp_mfma_kernel(
    const unsigned short* __restrict__ in_bf,
    const float* __restrict__ in_f32,
    const unsigned short* __restrict__ attn_bf,
    const float* __restrict__ den,
    unsigned short* __restrict__ hbf_out,
    const unsigned short* __restrict__ W1p, const unsigned short* __restrict__ W2p,
    const float* __restrict__ b1, const float* __restrict__ g,
    const float* __restrict__ be, const float* __restrict__ b2,
    OUT* __restrict__ out, int nrows)
{
    constexpr int NPASS = DIN / 128;
    struct Smem {
        union __align__(16) {
            unsigned short a1[128][136];
            unsigned short a2[128][136];
        } u;
        float2 gbuf[128];
        float  b1buf[128], b2buf[128];
        float2 lnred[4][64];
        float2 lnstat[128];
    };
    __shared__ Smem sm;

    const int tid = threadIdx.x;
    const int w = tid >> 6, l = tid & 63, lg = l >> 4, li = l & 15;
    const int rt = w >> 1, ct = w & 1;
    const long r0 = (long)blockIdx.x * 128;

    if (tid < 128) {
        sm.gbuf[tid]  = make_float2(g[tid], be[tid]);
        sm.b1buf[tid] = b1[tid];
        sm.b2buf[tid] = b2[tid];
    }

    const int se = tid >> 1, sp = tid & 1;
    long srg = r0 + se; if (srg >= nrows) srg = nrows - 1;

    f32x4 acc[4][4];
    #pragma unroll
    for (int mt = 0; mt < 4; ++mt)
        #pragma unroll
        for (int et = 0; et < 4; ++et)
            acc[mt][et] = (f32x4){0.f, 0.f, 0.f, 0.f};

    #pragma unroll
    for (int pass = 0; pass < NPASS; ++pass) {
        if constexpr (NPASS == 2) {
            if (pass == 0) {
                float inv[8];
                const float4* dp = (const float4*)(den + (size_t)srg * 16 + sp * 8);
                float4 d0 = dp[0], d1 = dp[1];
                inv[0] = d0.x > 0.f ? 1.f / d0.x : 0.f;
                inv[1] = d0.y > 0.f ? 1.f / d0.y : 0.f;
                inv[2] = d0.z > 0.f ? 1.f / d0.z : 0.f;
                inv[3] = d0.w > 0.f ? 1.f / d0.w : 0.f;
                inv[4] = d1.x > 0.f ? 1.f / d1.x : 0.f;
                inv[5] = d1.y > 0.f ? 1.f / d1.y : 0.f;
                inv[6] = d1.z > 0.f ? 1.f / d1.z : 0.f;
                inv[7] = d1.w > 0.f ? 1.f / d1.w : 0.f;
                const int4* ap = (const int4*)(attn_bf + (size_t)srg * 128 + sp * 64);
                #pragma unroll
                for (int i = 0; i < 8; ++i) {
                    int4 raw = ap[i];
                    const unsigned short* u = (const unsigned short*)&raw;
                    float iv = inv[i];
                    *(uint2*)&sm.u.a1[se][sp * 64 + i * 8] =
                        pack4bf(bf2f(u[0])*iv, bf2f(u[1])*iv, bf2f(u[2])*iv, bf2f(u[3])*iv);
                    *(uint2*)&sm.u.a1[se][sp * 64 + i * 8 + 4] =
                        pack4bf(bf2f(u[4])*iv, bf2f(u[5])*iv, bf2f(u[6])*iv, bf2f(u[7])*iv);
                }
            } else {
                const int4* s = (const int4*)(in_bf + (size_t)srg * 128 + sp * 64);
                int4* d = (int4*)&sm.u.a1[se][sp * 64];
                #pragma unroll
                for (int i = 0; i < 8; ++i) d[i] = s[i];
            }
        } else {
            const float4* af = (const float4*)(in_f32 + (size_t)srg * 128 + sp * 64);
            int4 tmp4[8];
            uint2* tp = (uint2*)tmp4;
            #pragma unroll
            for (int i = 0; i < 16; ++i) {
                float4 v = af[i];
                tp[i] = pack4bf(v.x, v.y, v.z, v.w);
            }
            int4* ldst = (int4*)&sm.u.a1[se][sp * 64];
            int4* gdst = (int4*)(hbf_out + (size_t)srg * 128 + sp * 64);
            #pragma unroll
            for (int k = 0; k < 8; ++k) { ldst[k] = tmp4[k]; gdst[k] = tmp4[k]; }
        }
        __syncthreads();

        #pragma unroll
        for (int kb = 0; kb < 4; ++kb) {
            bf16x8 wf[4], bfr[4];
            #pragma unroll
            for (int mt = 0; mt < 4; ++mt)
                wf[mt] = *(const bf16x8*)(W1p +
                    ((size_t)((pass * 4 + kb) * 8 + ct * 4 + mt) * 512 + l * 8));
            #pragma unroll
            for (int et = 0; et < 4; ++et)
                bfr[et] = *(const bf16x8*)(&sm.u.a1[rt * 64 + et * 16 + li][kb * 32 + lg * 8]);
            #pragma unroll
            for (int mt = 0; mt < 4; ++mt)
                #pragma unroll
                for (int et = 0; et < 4; ++et)
                    acc[mt][et] = __builtin_amdgcn_mfma_f32_16x16x32_bf16(
                        wf[mt], bfr[et], acc[mt][et], 0, 0, 0);
        }
        __syncthreads();
    }

    #pragma unroll
    for (int mt = 0; mt < 4; ++mt)
        #pragma unroll
        for (int r = 0; r < 4; ++r) {
            float b1v = sm.b1buf[ct * 64 + mt * 16 + lg * 4 + r];
            #pragma unroll
            for (int et = 0; et < 4; ++et) acc[mt][et][r] += b1v;
        }
    #pragma unroll
    for (int et = 0; et < 4; ++et) {
        float s = 0.f, sq = 0.f;
        #pragma unroll
        for (int mt = 0; mt < 4; ++mt)
            #pragma unroll
            for (int r = 0; r < 4; ++r) {
                float x = acc[mt][et][r];
                s += x; sq += x * x;
            }
        s  += __shfl_xor(s, 16, 64);  sq += __shfl_xor(sq, 16, 64);
        s  += __shfl_xor(s, 32, 64);  sq += __shfl_xor(sq, 32, 64);
        if (lg == 0) sm.lnred[w][et * 16 + li] = make_float2(s, sq);
    }
    __syncthreads();
    if (tid < 128) {
        int row = tid, rr = row >> 6;
        float2 p0 = sm.lnred[rr * 2][row & 63], p1 = sm.lnred[rr * 2 + 1][row & 63];
        float mu  = (p0.x + p1.x) * (1.f / 128.f);
        float var = (p0.y + p1.y) * (1.f / 128.f) - mu * mu;
        sm.lnstat[row] = make_float2(mu, rsqrtf(var + LN_EPS));
    }
    __syncthreads();

    {
        float2 stat[4];
        #pragma unroll
        for (int et = 0; et < 4; ++et) stat[et] = sm.lnstat[rt * 64 + et * 16 + li];
        #pragma unroll
        for (int mt = 0; mt < 4; ++mt) {
            float2 gb[4];
            #pragma unroll
            for (int r = 0; r < 4; ++r) gb[r] = sm.gbuf[ct * 64 + mt * 16 + lg * 4 + r];
            #pragma unroll
            for (int et = 0; et < 4; ++et) {
                float x0 = fmaxf(fmaf((acc[mt][et][0] - stat[et].x) * stat[et].y, gb[0].x, gb[0].y), 0.f);
                float x1 = fmaxf(fmaf((acc[mt][et][1] - stat[et].x) * stat[et].y, gb[1].x, gb[1].y), 0.f);
                float x2 = fmaxf(fmaf((acc[mt][et][2] - stat[et].x) * stat[et].y, gb[2].x, gb[2].y), 0.f);
                float x3 = fmaxf(fmaf((acc[mt][et][3] - stat[et].x) * stat[et].y, gb[3].x, gb[3].y), 0.f);
                *(uint2*)&sm.u.a2[rt * 64 + et * 16 + li][ct * 64 + mt * 16 + lg * 4] =
                    pack4bf(x0, x1, x2, x3);
            }
        }
    }
    __syncthreads();

    #pragma unroll
    for (int mt = 0; mt < 4; ++mt)
        #pragma unroll
        for (int et = 0; et < 4; ++et)
            acc[mt][et] = (f32x4){0.f, 0.f, 0.f, 0.f};

    for (int kb = 0; kb < 4; ++kb) {
        bf16x8 wf[4], bfr[4];
        #pragma unroll
        for (int mt = 0; mt < 4; ++mt)
            wf[mt] = *(const bf16x8*)(W2p + ((size_t)(kb * 8 + ct * 4 + mt) * 512 + l * 8));
        #pragma unroll
        for (int et = 0; et < 4; ++et)
            bfr[et] = *(const bf16x8*)(&sm.u.a2[rt * 64 + et * 16 + li][kb * 32 + lg * 8]);
        #pragma unroll
        for (int mt = 0; mt < 4; ++mt)
            #pragma unroll
            for (int et = 0; et < 4; ++et)
                acc[mt][et] = __builtin_amdgcn_mfma_f32_16x16x32_bf16(
                    wf[mt], bfr[et], acc[mt][et], 0, 0, 0);
    }

    float b2v[4][4];
    #pragma unroll
    for (int mt = 0; mt < 4; ++mt)
        #pragma unroll
        for (int r = 0; r < 4; ++r)
            b2v[mt][r] = sm.b2buf[ct * 64 + mt * 16 + lg * 4 + r];
    #pragma unroll
    for (int et = 0; et < 4; ++et) {
        long rg = r0 + rt * 64 + et * 16 + li;
        if (rg < nrows) {
            #pragma unroll
            for (int mt = 0; mt < 4; ++mt) {
                float y0 = acc[mt][et][0] + b2v[mt][0];
                float y1 = acc[mt][et][1] + b2v[mt][1];
                float y2 = acc[mt][et][2] + b2v[mt][2];
                float y3 = acc[mt][et][3] + b2v[mt][3];
                size_t o = (size_t)rg * 128 + ct * 64 + mt * 16 + lg * 4;
                if constexpr (sizeof(OUT) == 2) {
                    *(uint2*)(out + o) = pack4bf(y0, y1, y2, y3);
                } else {
                    float4 v = make_float4(y0, y1, y2, y3);
                    *(float4*)((float*)out + o) = v;
                }
            }
        }
    }
}

// ---------------------------------------------------------------------------
// Per-node precompute of the linear h-contributions to the fused kv layer-1:
//   Hds[n][0:256]   = h[n] @ W1fused[24:152]   (the h[dst] block)
//   Hds[n][256:512] = h[n] @ W1fused[152:280]  (the h[src] block)
// grid = (N/128, 4); gy selects a 128-col slice.  No bias, no LN (b1 is
// added once in the kv kernel).
// ---------------------------------------------------------------------------
__global__ __launch_bounds__(256, 2) void hd_hs_kernel(
    const unsigned short* __restrict__ h_bf,
    const unsigned short* __restrict__ W1h,
    unsigned short* __restrict__ Hds, int nrows)
{
    __shared__ unsigned short a1[128][136];
    const int tid = threadIdx.x;
    const int w = tid >> 6, l = tid & 63, lg = l >> 4, li = l & 15;
    const int rt = w >> 1, ct = w & 1;
    const long r0 = (long)blockIdx.x * 128;
    const int gy = blockIdx.y;

    {
        int se = tid >> 1, sp = tid & 1;
        long rg = r0 + se; if (rg >= nrows) rg = nrows - 1;
        const int4* s = (const int4*)(h_bf + (size_t)rg * 128 + sp * 64);
        int4* d = (int4*)&a1[se][sp * 64];
        #pragma unroll
        for (int i = 0; i < 8; ++i) d[i] = s[i];
    }
    __syncthreads();

    f32x4 acc[4][4];
    #pragma unroll
    for (int mt = 0; mt < 4; ++mt)
        #pragma unroll
        for (int et = 0; et < 4; ++et)
            acc[mt][et] = (f32x4){0.f, 0.f, 0.f, 0.f};

    const unsigned short* Wg = W1h + (size_t)gy * 16384;
    #pragma unroll
    for (int kb = 0; kb < 4; ++kb) {
        bf16x8 wf[4], bfr[4];
        #pragma unroll
        for (int mt = 0; mt < 4; ++mt)
            wf[mt] = *(const bf16x8*)(Wg + ((size_t)(kb * 8 + ct * 4 + mt) * 512 + l * 8));
        #pragma unroll
        for (int et = 0; et < 4; ++et)
            bfr[et] = *(const bf16x8*)(&a1[rt * 64 + et * 16 + li][kb * 32 + lg * 8]);
        #pragma unroll
        for (int mt = 0; mt < 4; ++mt)
            #pragma unroll
            for (int et = 0; et < 4; ++et)
                acc[mt][et] = __builtin_amdgcn_mfma_f32_16x16x32_bf16(
                    wf[mt], bfr[et], acc[mt][et], 0, 0, 0);
    }

    #pragma unroll
    for (int et = 0; et < 4; ++et) {
        long rg = r0 + rt * 64 + et * 16 + li;
        if (rg < nrows) {
            #pragma unroll
            for (int mt = 0; mt < 4; ++mt)
                *(uint2*)&Hds[(size_t)rg * 512 + gy * 128 + ct * 64 + mt * 16 + lg * 4] =
                    pack4bf(acc[mt][et][0], acc[mt][et][1], acc[mt][et][2], acc[mt][et][3]);
        }
    }
}

// ---------------------------------------------------------------------------
// MFMA edge kernel v2: 48 edges/block (LDS 38.5KB -> 4 blocks/CU), layer-1
// decomposed: X = Hd[dst] + Hs[src] gathered+staged (bf16), plus a single
// K=32 MFMA block for the edge/r features.  Rest (LN, ReLU, layer-2, scores,
// softmax-denominator atomics, pk-bf16 scatter) as before.
// ---------------------------------------------------------------------------
__global__ __launch_bounds__(256, 4) void kv_mfma_kernel(
    const unsigned short* __restrict__ Hds,    // [N][512] bf16: Hd | Hs
    const unsigned short* __restrict__ q_bf,   // [N][128] bf16
    const float* __restrict__ r_feat, const float* __restrict__ edge_feat,
    const float* __restrict__ e_w,
    const int* __restrict__ src_idx, const int* __restrict__ dst_idx,
    const unsigned short* __restrict__ B1e, const unsigned short* __restrict__ B2p,
    const float* __restrict__ kb1, const float* __restrict__ vb1,
    const float* __restrict__ kg,  const float* __restrict__ kbeta,
    const float* __restrict__ vg,  const float* __restrict__ vbeta,
    const float* __restrict__ kb2, const float* __restrict__ vb2,
    unsigned short* __restrict__ attn_bf, float* __restrict__ den, int E)
{
    struct Smem {
        union __align__(16) {
            struct {
                unsigned short x[48][264];    // Hd[dst]+Hs[src], 256 cols (+pad)
                unsigned short a1e[48][32];   // edge/r features, K=32 (24 real)
            } s1;                             // 28,416 B
            unsigned short a2[48][264];       // layer-2 input bf16
            float          kbuf[48][132];     // k output fp32
            float          vbuf[48][132];     // scaled v fp32
        } u;
        float  sex[48][17];
        float2 gbuf[256];
        float  b1buf[256], b2buf[256];
        float2 lnred[4][48];
        float2 lnstat[2][48];
        int    sdst[48];
        float  sew[48];
    };
    __shared__ Smem sm;

    const int tid = threadIdx.x;
    const int w  = tid >> 6, l = tid & 63, lg = l >> 4, li = l & 15;
    const long e0 = (long)blockIdx.x * 48;

    {
        int c = tid;
        float g  = (c < 128) ? kg[c]    : vg[c - 128];
        float be = (c < 128) ? kbeta[c] : vbeta[c - 128];
        sm.gbuf[c]  = make_float2(g, be);
        sm.b1buf[c] = (c < 128) ? kb1[c] : vb1[c - 128];
        sm.b2buf[c] = (c < 128) ? kb2[c] : vb2[c - 128];
    }

    // ---- staging: threads 0..191 build X = Hd[dst]+Hs[src] (bf16),
    //      threads 192..239 stage edge/r features + sdst/sew
    if (tid < 192) {
        int e = tid >> 2, qt = tid & 3;
        long eg = e0 + e; if (eg >= E) eg = E - 1;
        int d = dst_idx[eg], s = src_idx[eg];
        const int4* pd = (const int4*)(Hds + (size_t)d * 512 + qt * 64);
        const int4* ps = (const int4*)(Hds + (size_t)s * 512 + 256 + qt * 64);
        #pragma unroll
        for (int i = 0; i < 8; ++i) {
            int4 A = pd[i], B4 = ps[i];
            const unsigned int* ua = (const unsigned int*)&A;
            const unsigned int* ub = (const unsigned int*)&B4;
            unsigned int o[4];
            #pragma unroll
            for (int j = 0; j < 4; ++j) {
                float lo = __uint_as_float(ua[j] << 16) + __uint_as_float(ub[j] << 16);
                float hi = __uint_as_float(ua[j] & 0xffff0000u) +
                           __uint_as_float(ub[j] & 0xffff0000u);
                o[j] = (unsigned int)f2bf(lo) | ((unsigned int)f2bf(hi) << 16);
            }
            *(int4*)&sm.u.s1.x[e][qt * 64 + i * 8] = *(const int4*)o;
        }
    } else {
        int t = tid - 192;
        if (t < 48) {
            long eg = e0 + t; if (eg >= E) eg = E - 1;
            sm.sdst[t] = dst_idx[eg];
            sm.sew[t]  = e_w[eg];
            float4 ef = *(const float4*)(edge_feat + (size_t)eg * 4);
            *(uint2*)&sm.u.s1.a1e[t][0] = pack4bf(ef.x, ef.y, ef.z, ef.w);
            const float4* rf = (const float4*)(r_feat + (size_t)eg * 20);
            #pragma unroll
            for (int i = 0; i < 5; ++i) {
                float4 v = rf[i];
                *(uint2*)&sm.u.s1.a1e[t][4 + i * 4] = pack4bf(v.x, v.y, v.z, v.w);
            }
            int4 z = {0, 0, 0, 0};
            *(int4*)&sm.u.s1.a1e[t][24] = z;
        }
    }
    __syncthreads();

    f32x4 acc[4][3];
    #pragma unroll
    for (int mt = 0; mt < 4; ++mt)
        #pragma unroll
        for (int et = 0; et < 3; ++et)
            acc[mt][et] = (f32x4){0.f, 0.f, 0.f, 0.f};

    // ---- layer 1: single K=32 MFMA block (edge features)
    {
        bf16x8 wf[4], bfr[3];
        #pragma unroll
        for (int mt = 0; mt < 4; ++mt)
            wf[mt] = *(const bf16x8*)(B1e + ((size_t)(w * 4 + mt) * 512 + l * 8));
        #pragma unroll
        for (int et = 0; et < 3; ++et)
            bfr[et] = *(const bf16x8*)(&sm.u.s1.a1e[et * 16 + li][lg * 8]);
        #pragma unroll
        for (int mt = 0; mt < 4; ++mt)
            #pragma unroll
            for (int et = 0; et < 3; ++et)
                acc[mt][et] = __builtin_amdgcn_mfma_f32_16x16x32_bf16(
                    wf[mt], bfr[et], acc[mt][et], 0, 0, 0);
    }

    // ---- + X (precomputed h contributions) + b1
    #pragma unroll
    for (int mt = 0; mt < 4; ++mt) {
        float b1v[4];
        #pragma unroll
        for (int r = 0; r < 4; ++r) b1v[r] = sm.b1buf[w * 64 + mt * 16 + lg * 4 + r];
        #pragma unroll
        for (int et = 0; et < 3; ++et) {
            uint2 xv = *(const uint2*)&sm.u.s1.x[et * 16 + li][w * 64 + mt * 16 + lg * 4];
            acc[mt][et][0] += __uint_as_float(xv.x << 16)          + b1v[0];
            acc[mt][et][1] += __uint_as_float(xv.x & 0xffff0000u)  + b1v[1];
            acc[mt][et][2] += __uint_as_float(xv.y << 16)          + b1v[2];
            acc[mt][et][3] += __uint_as_float(xv.y & 0xffff0000u)  + b1v[3];
        }
    }

    // ---- LN partials
    #pragma unroll
    for (int et = 0; et < 3; ++et) {
        float s = 0.f, sq = 0.f;
        #pragma unroll
        for (int mt = 0; mt < 4; ++mt)
            #pragma unroll
            for (int r = 0; r < 4; ++r) {
                float x = acc[mt][et][r];
                s += x; sq += x * x;
            }
        s  += __shfl_xor(s, 16, 64);  sq += __shfl_xor(sq, 16, 64);
        s  += __shfl_xor(s, 32, 64);  sq += __shfl_xor(sq, 32, 64);
        if (lg == 0) sm.lnred[w][et * 16 + li] = make_float2(s, sq);
    }
    __syncthreads();
    if (tid < 128) {
        int half = tid >> 6, e = tid & 63;
        if (e < 48) {
            float2 p0 = sm.lnred[half * 2][e], p1 = sm.lnred[half * 2 + 1][e];
            float mu  = (p0.x + p1.x) * (1.f / 128.f);
            float var = (p0.y + p1.y) * (1.f / 128.f) - mu * mu;
            sm.lnstat[half][e] = make_float2(mu, rsqrtf(var + LN_EPS));
        }
    }
    __syncthreads();

    // ---- normalize + ReLU -> a2 (bf16)
    {
        float2 stat[3];
        #pragma unroll
        for (int et = 0; et < 3; ++et) stat[et] = sm.lnstat[w >> 1][et * 16 + li];
        #pragma unroll
        for (int mt = 0; mt < 4; ++mt) {
            float2 gb[4];
            #pragma unroll
            for (int r = 0; r < 4; ++r) gb[r] = sm.gbuf[w * 64 + mt * 16 + lg * 4 + r];
            #pragma unroll
            for (int et = 0; et < 3; ++et) {
                float x0 = fmaxf(fmaf((acc[mt][et][0] - stat[et].x) * stat[et].y, gb[0].x, gb[0].y), 0.f);
                float x1 = fmaxf(fmaf((acc[mt][et][1] - stat[et].x) * stat[et].y, gb[1].x, gb[1].y), 0.f);
                float x2 = fmaxf(fmaf((acc[mt][et][2] - stat[et].x) * stat[et].y, gb[2].x, gb[2].y), 0.f);
                float x3 = fmaxf(fmaf((acc[mt][et][3] - stat[et].x) * stat[et].y, gb[3].x, gb[3].y), 0.f);
                *(uint2*)&sm.u.a2[et * 16 + li][w * 64 + mt * 16 + lg * 4] = pack4bf(x0, x1, x2, x3);
            }
        }
    }
    __syncthreads();

    // ---- layer 2
    #pragma unroll
    for (int mt = 0; mt < 4; ++mt)
        #pragma unroll
        for (int et = 0; et < 3; ++et)
            acc[mt][et] = (f32x4){0.f, 0.f, 0.f, 0.f};

    const int koff = (w < 2) ? 0 : 128;
    for (int kb = 0; kb < 4; ++kb) {
        bf16x8 wf[4], bfr[3];
        #pragma unroll
        for (int mt = 0; mt < 4; ++mt)
            wf[mt] = *(const bf16x8*)(B2p + ((size_t)(kb * 16 + w * 4 + mt) * 512 + l * 8));
        #pragma unroll
        for (int et = 0; et < 3; ++et)
            bfr[et] = *(const bf16x8*)(&sm.u.a2[et * 16 + li][koff + kb * 32 + lg * 8]);
        #pragma unroll
        for (int mt = 0; mt < 4; ++mt)
            #pragma unroll
            for (int et = 0; et < 3; ++et)
                acc[mt][et] = __builtin_amdgcn_mfma_f32_16x16x32_bf16(
                    wf[mt], bfr[et], acc[mt][et], 0, 0, 0);
    }
    #pragma unroll
    for (int mt = 0; mt < 4; ++mt)
        #pragma unroll
        for (int r = 0; r < 4; ++r) {
            float b2v = sm.b2buf[w * 64 + mt * 16 + lg * 4 + r];
            #pragma unroll
            for (int et = 0; et < 3; ++et) acc[mt][et][r] += b2v;
        }
    __syncthreads();   // all a2 reads done before kbuf overwrites the union

    // ---- waves 0,1 stash k (fp32) to LDS; waves 2,3 keep v in registers
    if (w < 2) {
        #pragma unroll
        for (int mt = 0; mt < 4; ++mt)
            #pragma unroll
            for (int et = 0; et < 3; ++et)
                *(f32x4*)&sm.u.kbuf[et * 16 + li][w * 64 + mt * 16 + lg * 4] = acc[mt][et];
    }
    __syncthreads();

    // ---- scores: 48 edges x 16 heads
    {
        int e = tid >> 2, hb = (tid & 3) * 4;
        if (e < 48) {
            long eg = e0 + e;
            int d = sm.sdst[e];
            const int4* qp = (const int4*)(q_bf + (size_t)d * 128 + hb * 8);
            int4 q4[4];
            #pragma unroll
            for (int i = 0; i < 4; ++i) q4[i] = qp[i];
            if (eg < E) {
                #pragma unroll
                for (int hh = 0; hh < 4; ++hh) {
                    const float* kr = &sm.u.kbuf[e][(hb + hh) * 8];
                    const unsigned short* qq = (const unsigned short*)&q4[hh];
                    float sc = 0.f;
                    #pragma unroll
                    for (int t = 0; t < 8; ++t) sc = fmaf(kr[t], bf2f(qq[t]), sc);
                    sc *= 0.35355339059327373f;   // 1/sqrt(8)
                    float exv = __expf(sc);
                    sm.sex[e][hb + hh] = exv;
                    unsafeAtomicAdd(&den[(size_t)d * 16 + hb + hh], exv);
                }
            }
        }
    }
    __syncthreads();   // sex ready; kbuf fully consumed

    // ---- waves 2,3: scale v by ex*e_w, stage to vbuf
    if (w >= 2) {
        #pragma unroll
        for (int et = 0; et < 3; ++et) {
            int e = et * 16 + li;
            long eg = e0 + e;
            float ew = (eg < E) ? sm.sew[e] : 0.f;
            #pragma unroll
            for (int mt = 0; mt < 4; ++mt) {
                int cbase = (w - 2) * 64 + mt * 16 + lg * 4;
                float scale = ew * sm.sex[e][cbase >> 3];
                f32x4 v = acc[mt][et];
                v[0] *= scale; v[1] *= scale; v[2] *= scale; v[3] *= scale;
                *(f32x4*)&sm.u.vbuf[e][cbase] = v;
            }
        }
    }
    __syncthreads();

    // ---- coalesced bf16 scatter: one wave per edge row (12 per wave)
    {
        #pragma unroll
        for (int j = 0; j < 12; ++j) {
            int e = w * 12 + j;
            long eg = e0 + e;
            if (eg < E) {
                int d = sm.sdst[e];
                float2 vv = *(const float2*)&sm.u.vbuf[e][l * 2];
                unsigned int pk = (unsigned int)f2bf(vv.x) |
                                  ((unsigned int)f2bf(vv.y) << 16);
                unsigned short* addr = attn_bf + (size_t)d * 128 + l * 2;
                asm volatile("global_atomic_pk_add_bf16 %0, %1, off"
                             :: "v"(addr), "v"(pk) : "memory");
            }
        }
    }
}

// ---------------------------------------------------------------------------
extern "C" void kernel_launch(void* const* d_in, const int* in_sizes, int n_in,
                              void* d_out, int out_size, void* d_ws, size_t ws_size,
                              hipStream_t stream)
{
    const float* h         = (const float*)d_in[0];
    const float* r_feat    = (const float*)d_in[1];
    const float* edge_feat = (const float*)d_in[2];
    const int*   edge_idx  = (const int*)d_in[3];
    const float* e_w       = (const float*)d_in[4];
    const float* P[24];
    for (int i = 0; i < 24; ++i) P[i] = (const float*)d_in[5 + i];
    // P[0..5]=xk{W1,b1,g,beta,W2,b2}  P[6..11]=xv  P[12..17]=xq  P[18..23]=out

    const int N = in_sizes[0] / 128;
    const int E = in_sizes[4];
    const int* src = edge_idx;
    const int* dst = edge_idx + E;

    // workspace carve
    char* p = (char*)d_ws;
    unsigned short* h_bf = (unsigned short*)p; p += (size_t)N * 128 * 2;
    unsigned short* q_bf = (unsigned short*)p; p += (size_t)N * 128 * 2;
    unsigned short* B1e  = (unsigned short*)p; p += (size_t)1024 * 8 * 2;
    unsigned short* B2p  = (unsigned short*)p; p += (size_t)4096 * 8 * 2;
    unsigned short* W1h  = (unsigned short*)p; p += (size_t)8192 * 8 * 2;
    unsigned short* W1q  = (unsigned short*)p; p += (size_t)2048 * 8 * 2;
    unsigned short* W2q  = (unsigned short*)p; p += (size_t)2048 * 8 * 2;
    unsigned short* W1o  = (unsigned short*)p; p += (size_t)4096 * 8 * 2;
    unsigned short* W2o  = (unsigned short*)p; p += (size_t)2048 * 8 * 2;
    unsigned short* Hds  = (unsigned short*)p; p += (size_t)N * 512 * 2;
    unsigned short* attn_bf = (unsigned short*)p; p += (size_t)N * 128 * 2;
    float* den           = (float*)p;          p += (size_t)N * 16 * 4;

    // zero attn_bf + den (adjacent)
    hipMemsetAsync(attn_bf, 0, (size_t)N * (128 * 2 + 16 * 4), stream);

    // pack all weights in one dispatch
    pack_all_kernel<<<dim3(92), dim3(256), 0, stream>>>(
        P[0], P[6], P[4], P[10], P[12], P[16], P[18], P[22],
        B1e, B2p, W1h, W1q, W2q, W1o, W2o);

    // q = MLP_xq(h) -> bf16 (MFMA); also emits h_bf (fused f32->bf16)
    node_mlp_mfma_kernel<128, unsigned short><<<dim3((N + 127) / 128), dim3(256), 0, stream>>>(
        nullptr, h, nullptr, nullptr, h_bf,
        W1q, W2q, P[13], P[14], P[15], P[17], q_bf, N);

    // per-node linear layer-1 contributions Hd|Hs
    hd_hs_kernel<<<dim3((N + 127) / 128, 4), dim3(256), 0, stream>>>(h_bf, W1h, Hds, N);

    // per-edge fused k/v MLPs (decomposed layer-1) + scores + den + scatter
    kv_mfma_kernel<<<dim3((E + 47) / 48), dim3(256), 0, stream>>>(
        Hds, q_bf, r_feat, edge_feat, e_w, src, dst, B1e, B2p,
        P[1], P[7], P[2], P[3], P[8], P[9], P[5], P[11],
        attn_bf, den, E);

    // final = MLP_out([attn/den | h])
    node_mlp_mfma_kernel<256, float><<<dim3((N + 127) / 128), dim3(256), 0, stream>>>(
        h_bf, nullptr, attn_bf, den, nullptr,
        W1o, W2o, P[19], P[20], P[21], P[23], (float*)d_out, N);
}